// Round 4
// baseline (548.682 us; speedup 1.0000x reference)
//
#include <hip/hip_runtime.h>

// ---------------------------------------------------------------------------
// FUSED 2-layer LSTM (Keras gates i,f,g,o) + Dense(27) + softmax. fp32.
// B=32768, T=21, F=126, U=8.
//
// R8: kill W-load addressing VALU. R6 counters: 217us x 52% VALUBusy =>
// ~3200 VALU instr/wave/t vs ~1100 of real math; ~950/t is 64-bit vector
// address arithmetic for the per-q W1k global loads (compiler did not
// scalarize the wave-uniform reads). Fix: stage W1k in LDS ONCE (16KB,
// persists across t); GEMM reads W via broadcast ds_read_b128 at
// compile-time immediate offsets from one wave-uniform base (zero
// address VALU), x via ds_read_b64 base+imm. Recurrent weights (3KB)
// stay global/L1 as float4.
//
// Structure (from R7): block=512thr=8 waves, wave=(colgrp x fhalf);
// f-split GEMM partials summed via the z1 LDS exchange; role-split
// recurrence (fh0: LSTM1 + h1@W1r + h1@W2k, fh1: LSTM2 + h2@W2r);
// 2 barriers/t; single x buffer (drain in Ba..Bb window).
//
// LDS: wlds 16128 + xb 32256 + zb1 16384 + zb2 16384 = 81152 B
//   -> 2 blocks/CU (162304 <= 163840) = 16 waves/CU = 4 waves/SIMD.
// __launch_bounds__(512,4) pins VGPR<=128 so VGPR doesn't cap below LDS.
// ---------------------------------------------------------------------------

namespace {
constexpr int T_  = 21;
constexpr int FIN = 126;
constexpr int U_  = 8;
constexpr int NC  = 27;
constexpr int ZC  = 4 * U_;              // 32 gate columns
constexpr int ROW = T_ * FIN;            // 2646 floats per sample
constexpr int NT  = 512;                 // threads per block (8 waves)
constexpr int NPF = 8;                   // float2 staged per thread
}

__device__ __forceinline__ float sigm(float x) {
  return __builtin_amdgcn_rcpf(1.0f + __expf(-x));
}
__device__ __forceinline__ float tanh_f(float x) {
  return 1.0f - 2.0f * __builtin_amdgcn_rcpf(1.0f + __expf(2.0f * x));
}

__global__ __launch_bounds__(NT, 4) void lstm_fused(
    const float* __restrict__ X,
    const float* __restrict__ W1k, const float* __restrict__ b1,
    const float* __restrict__ W1r,
    const float* __restrict__ W2k, const float* __restrict__ W2r,
    const float* __restrict__ b2,
    const float* __restrict__ Wd, const float* __restrict__ bd,
    float* __restrict__ out)
{
  __shared__ __align__(16) float wlds[FIN * ZC];      // 16128 B, W1k row-major
  __shared__ __align__(16) float xb[64 * FIN];        // 32256 B, single buffer
  // z exchanges: [col][half][sample]; the 2 partials sit 64 floats apart.
  __shared__ __align__(16) float zb1[ZC * 2 * 64];    // 16384 B
  __shared__ __align__(16) float zb2[ZC * 2 * 64];    // 16384 B

  const int tid = threadIdx.x;
  const int sl  = tid & 63;                                   // sample lane
  const int wv  = __builtin_amdgcn_readfirstlane(tid >> 6);   // 0..7
  const int cg  = wv & 3;        // column group: cols [8cg, 8cg+8)
  const int fh  = wv >> 2;       // f half: 0 -> q in [0,32), 1 -> q in [32,63)
  const int grp = blockIdx.x;

  // staging decomposition: j over 64*63 float2 elems, 8 per thread
  int  goff[NPF];
  int  loff[NPF];
  bool val[NPF];
  #pragma unroll
  for (int k = 0; k < NPF; ++k) {
    int j = tid + k * NT;
    val[k] = (j < 64 * 63);
    int s = j / 63;
    int q = j - s * 63;
    goff[k] = s * ROW + 2 * q;
    loff[k] = s * FIN + 2 * q;
  }

  const float* xbase = X + (size_t)grp * 64 * ROW;

  // recurrent weights for this wave's role (fh0: layer1, fh1: layer2)
  const float*  Wrr = (fh == 0) ? W1r : W2r;
  const float4  b1a = reinterpret_cast<const float4*>(b1)[2 * cg];
  const float4  b1b = reinterpret_cast<const float4*>(b1)[2 * cg + 1];
  const float4  b2a = reinterpret_cast<const float4*>(b2)[2 * cg];
  const float4  b2b = reinterpret_cast<const float4*>(b2)[2 * cg + 1];

  // role-overlaid state: fh0 -> (h1,c1), fh1 -> (h2,c2)
  float hs[U_], cs[U_];
  #pragma unroll
  for (int u = 0; u < U_; ++u) { hs[u] = 0.f; cs[u] = 0.f; }

  // prologue: stage W1k (2016 float2) + x(0) into LDS; prefetch x(1)
  {
    const float2* w2 = reinterpret_cast<const float2*>(W1k);
    #pragma unroll
    for (int k = 0; k < 4; ++k) {
      int j = tid + k * NT;
      if (j < (FIN * ZC) / 2)
        reinterpret_cast<float2*>(wlds)[j] = w2[j];
    }
  }
  float2 pf[NPF];
  #pragma unroll
  for (int k = 0; k < NPF; ++k)
    if (val[k]) pf[k] = *reinterpret_cast<const float2*>(xbase + goff[k]);
  #pragma unroll
  for (int k = 0; k < NPF; ++k)
    if (val[k]) *reinterpret_cast<float2*>(&xb[loff[k]]) = pf[k];
  {
    const float* xt = xbase + FIN;
    #pragma unroll
    for (int k = 0; k < NPF; ++k)
      if (val[k]) pf[k] = *reinterpret_cast<const float2*>(xt + goff[k]);
  }
  __syncthreads();

  // wave-uniform LDS bases: all GEMM accesses are base + immediate offset
  const float* wl = &wlds[8 * cg];
  const float* xr = &xb[sl * FIN];

  for (int t = 0; t < T_; ++t) {
    // ---- layer-1 GEMM partial over this wave's f-half ----
    float4 za, zbv;
    if (fh == 0) { za = b1a; zbv = b1b; }
    else {
      za  = make_float4(0.f, 0.f, 0.f, 0.f);
      zbv = make_float4(0.f, 0.f, 0.f, 0.f);
    }

    auto run_gemm = [&](const int q0, const int qn) {
      #pragma unroll 4
      for (int qq = 0; qq < qn; ++qq) {
        const int q = q0 + qq;
        float2 xv  = *reinterpret_cast<const float2*>(&xr[2 * q]);
        float4 wa0 = *reinterpret_cast<const float4*>(&wl[(2 * q) * ZC]);
        float4 wb0 = *reinterpret_cast<const float4*>(&wl[(2 * q) * ZC + 4]);
        float4 wa1 = *reinterpret_cast<const float4*>(&wl[(2 * q + 1) * ZC]);
        float4 wb1 = *reinterpret_cast<const float4*>(&wl[(2 * q + 1) * ZC + 4]);
        za.x  = fmaf(xv.x, wa0.x, za.x);  za.y  = fmaf(xv.x, wa0.y, za.y);
        za.z  = fmaf(xv.x, wa0.z, za.z);  za.w  = fmaf(xv.x, wa0.w, za.w);
        zbv.x = fmaf(xv.x, wb0.x, zbv.x); zbv.y = fmaf(xv.x, wb0.y, zbv.y);
        zbv.z = fmaf(xv.x, wb0.z, zbv.z); zbv.w = fmaf(xv.x, wb0.w, zbv.w);
        za.x  = fmaf(xv.y, wa1.x, za.x);  za.y  = fmaf(xv.y, wa1.y, za.y);
        za.z  = fmaf(xv.y, wa1.z, za.z);  za.w  = fmaf(xv.y, wa1.w, za.w);
        zbv.x = fmaf(xv.y, wb1.x, zbv.x); zbv.y = fmaf(xv.y, wb1.y, zbv.y);
        zbv.z = fmaf(xv.y, wb1.z, zbv.z); zbv.w = fmaf(xv.y, wb1.w, zbv.w);
      }
    };
    if (fh == 0) run_gemm(0, 32);
    else         run_gemm(32, 31);

    // fh0 adds the layer-1 recurrent term h1(t-1) @ W1r
    if (fh == 0) {
      #pragma unroll
      for (int k = 0; k < U_; ++k) {
        float hv = hs[k];
        const float4* w = reinterpret_cast<const float4*>(&Wrr[k * ZC + 8 * cg]);
        float4 w0 = w[0], w1 = w[1];
        za.x  = fmaf(hv, w0.x, za.x);  za.y  = fmaf(hv, w0.y, za.y);
        za.z  = fmaf(hv, w0.z, za.z);  za.w  = fmaf(hv, w0.w, za.w);
        zbv.x = fmaf(hv, w1.x, zbv.x); zbv.y = fmaf(hv, w1.y, zbv.y);
        zbv.z = fmaf(hv, w1.z, zbv.z); zbv.w = fmaf(hv, w1.w, zbv.w);
      }
    }

    // write z1 partial: zb1[(col)*128 + fh*64 + sl]
    {
      float* zp = &zb1[(8 * cg) * 128 + fh * 64 + sl];
      zp[0 * 128] = za.x;  zp[1 * 128] = za.y;  zp[2 * 128] = za.z;  zp[3 * 128] = za.w;
      zp[4 * 128] = zbv.x; zp[5 * 128] = zbv.y; zp[6 * 128] = zbv.z; zp[7 * 128] = zbv.w;
    }
    __syncthreads();                                   // Ba: z1 visible, x reads done

    // drain x(t+1) into LDS (window Ba..Bb), issue prefetch of x(t+2)
    if (t + 1 < T_) {
      #pragma unroll
      for (int k = 0; k < NPF; ++k)
        if (val[k]) *reinterpret_cast<float2*>(&xb[loff[k]]) = pf[k];
    }
    if (t + 2 < T_) {
      const float* xt = xbase + (size_t)(t + 2) * FIN;
      #pragma unroll
      for (int k = 0; k < NPF; ++k)
        if (val[k]) pf[k] = *reinterpret_cast<const float2*>(xt + goff[k]);
    }

    if (fh == 0) {
      // ---- LSTM1 update (fh0 waves; z1 = sum of 2 partials) ----
      #pragma unroll
      for (int u = 0; u < U_; ++u) {
        const float* p0 = &zb1[u * 128 + sl];
        float zi = p0[0]        + p0[64];
        float zf = p0[ 8 * 128] + p0[ 8 * 128 + 64];
        float zg = p0[16 * 128] + p0[16 * 128 + 64];
        float zo = p0[24 * 128] + p0[24 * 128 + 64];
        float iv = sigm(zi), fv = sigm(zf), gv = tanh_f(zg), ov = sigm(zo);
        float cn = fv * cs[u] + iv * gv;
        cs[u] = cn;
        hs[u] = ov * tanh_f(cn);
      }
      // z2 feed-forward partial: b2 + h1 @ W2k (this wave's 8 cols)
      float4 za2 = b2a, zb2v = b2b;
      #pragma unroll
      for (int k = 0; k < U_; ++k) {
        float hv = hs[k];
        const float4* w = reinterpret_cast<const float4*>(&W2k[k * ZC + 8 * cg]);
        float4 w0 = w[0], w1 = w[1];
        za2.x  = fmaf(hv, w0.x, za2.x);  za2.y  = fmaf(hv, w0.y, za2.y);
        za2.z  = fmaf(hv, w0.z, za2.z);  za2.w  = fmaf(hv, w0.w, za2.w);
        zb2v.x = fmaf(hv, w1.x, zb2v.x); zb2v.y = fmaf(hv, w1.y, zb2v.y);
        zb2v.z = fmaf(hv, w1.z, zb2v.z); zb2v.w = fmaf(hv, w1.w, zb2v.w);
      }
      float* zp = &zb2[(8 * cg) * 128 + 0 * 64 + sl];
      zp[0 * 128] = za2.x;  zp[1 * 128] = za2.y;  zp[2 * 128] = za2.z;  zp[3 * 128] = za2.w;
      zp[4 * 128] = zb2v.x; zp[5 * 128] = zb2v.y; zp[6 * 128] = zb2v.z; zp[7 * 128] = zb2v.w;
    } else {
      // z2 recurrent partial: h2(t-1) @ W2r (this wave's 8 cols)
      float4 za2  = make_float4(0.f, 0.f, 0.f, 0.f);
      float4 zb2v = make_float4(0.f, 0.f, 0.f, 0.f);
      #pragma unroll
      for (int k = 0; k < U_; ++k) {
        float hv = hs[k];
        const float4* w = reinterpret_cast<const float4*>(&Wrr[k * ZC + 8 * cg]);
        float4 w0 = w[0], w1 = w[1];
        za2.x  = fmaf(hv, w0.x, za2.x);  za2.y  = fmaf(hv, w0.y, za2.y);
        za2.z  = fmaf(hv, w0.z, za2.z);  za2.w  = fmaf(hv, w0.w, za2.w);
        zb2v.x = fmaf(hv, w1.x, zb2v.x); zb2v.y = fmaf(hv, w1.y, zb2v.y);
        zb2v.z = fmaf(hv, w1.z, zb2v.z); zb2v.w = fmaf(hv, w1.w, zb2v.w);
      }
      float* zp = &zb2[(8 * cg) * 128 + 1 * 64 + sl];
      zp[0 * 128] = za2.x;  zp[1 * 128] = za2.y;  zp[2 * 128] = za2.z;  zp[3 * 128] = za2.w;
      zp[4 * 128] = zb2v.x; zp[5 * 128] = zb2v.y; zp[6 * 128] = zb2v.z; zp[7 * 128] = zb2v.w;
    }
    __syncthreads();                                   // Bb: z2 + x(t+1) visible

    if (fh == 1) {
      // ---- LSTM2 update (fh1 waves; z2 = sum of 2 partials) ----
      #pragma unroll
      for (int u = 0; u < U_; ++u) {
        const float* p0 = &zb2[u * 128 + sl];
        float zi = p0[0]        + p0[64];
        float zf = p0[ 8 * 128] + p0[ 8 * 128 + 64];
        float zg = p0[16 * 128] + p0[16 * 128 + 64];
        float zo = p0[24 * 128] + p0[24 * 128 + 64];
        float iv = sigm(zi), fv = sigm(zf), gv = tanh_f(zg), ov = sigm(zo);
        float cn = fv * cs[u] + iv * gv;
        cs[u] = cn;
        hs[u] = ov * tanh_f(cn);
      }
    }
  }

  // ---- Dense(27) + softmax: fh1 waves hold h2(T-1); wave 4 stages ----
  if (wv == 4) {
    float lg[NC];
    float m = -1e30f;
    #pragma unroll
    for (int c = 0; c < NC; ++c) {
      float acc = bd[c];
      #pragma unroll
      for (int k = 0; k < U_; ++k) acc = fmaf(hs[k], Wd[k * NC + c], acc);
      lg[c] = acc;
      m = fmaxf(m, acc);
    }
    float ssum = 0.f;
    #pragma unroll
    for (int c = 0; c < NC; ++c) {
      float e = __expf(lg[c] - m);
      lg[c] = e;
      ssum += e;
    }
    float inv = 1.0f / ssum;
    #pragma unroll
    for (int c = 0; c < NC; ++c) zb1[sl * NC + c] = lg[c] * inv;
  }
  __syncthreads();
  {
    float* oblk = out + (size_t)grp * 64 * NC;
    #pragma unroll
    for (int k = 0; k < 4; ++k) {
      int j = tid + k * NT;
      if (j < 64 * NC) oblk[j] = zb1[j];   // coalesced store
    }
  }
}

extern "C" void kernel_launch(void* const* d_in, const int* in_sizes, int n_in,
                              void* d_out, int out_size, void* d_ws, size_t ws_size,
                              hipStream_t stream) {
  const float* X   = (const float*)d_in[0];
  const float* W1k = (const float*)d_in[1];
  const float* W1r = (const float*)d_in[2];
  const float* b1  = (const float*)d_in[3];
  const float* W2k = (const float*)d_in[4];
  const float* W2r = (const float*)d_in[5];
  const float* b2  = (const float*)d_in[6];
  const float* Wd  = (const float*)d_in[7];
  const float* bd  = (const float*)d_in[8];
  float* out = (float*)d_out;
  (void)d_ws; (void)ws_size;   // workspace intentionally unused (fused design)

  const int B    = in_sizes[0] / ROW;   // 32768
  const int ngrp = B / 64;              // 512

  lstm_fused<<<dim3(ngrp), NT, 0, stream>>>(
      X, W1k, b1, W1r, W2k, W2r, b2, Wd, bd, out);
}